// Round 3
// baseline (199.841 us; speedup 1.0000x reference)
//
#include <hip/hip_runtime.h>
#include <stdint.h>

// Problem constants
//  B = 32768 samples, T_X = 4, K = 128, 64 groups x 512, out = (64,128,1,1024) fp32
typedef __attribute__((ext_vector_type(8))) short bf16x8;  // 8 bf16 in 4 VGPRs
typedef __attribute__((ext_vector_type(4))) float f32x4;

__device__ __forceinline__ unsigned short f2bf(float x) {
    union { float f; uint32_t u; } v; v.f = x;
    uint32_t r = v.u + 0x7FFFu + ((v.u >> 16) & 1u);   // RNE
    return (unsigned short)(r >> 16);
}
__device__ __forceinline__ uint32_t pack2bf(float a, float b) {
    return (uint32_t)f2bf(a) | ((uint32_t)f2bf(b) << 16);
}
__device__ __forceinline__ float bf2f(uint32_t lo) {
    union { uint32_t u; float f; } v; v.u = lo << 16; return v.f;
}
__device__ __forceinline__ float lrelu(float v) { return v > 0.f ? v : 0.01f * v; }

// ---------------------------------------------------------------------------
// K0: precompute (LDS-tiled small GEMMs, coalesced staging, split hi/lo out)
//   G[i][j]  = (1/sqrt(128)) * sum_o Wk[o,i]*Wq[o,j]             (128x128)
//   M[o][c]  = inv_sqrt2 * sum_k conv_w[o, (c>>7)*128+k]*Wv[k, c&127] (128x256)
//   blocks 0..63: G 16x16 tiles; 64..191: M 16x16 tiles; 192: BN constants
// ---------------------------------------------------------------------------
__global__ __launch_bounds__(256) void precompute_kernel(
    const float* __restrict__ Wq, const float* __restrict__ Wk,
    const float* __restrict__ Wv, const float* __restrict__ conv_w,
    const float* __restrict__ conv_b, const float* __restrict__ bn_gamma,
    const float* __restrict__ bn_beta, const float* __restrict__ bn_mean,
    const float* __restrict__ bn_var,
    unsigned short* __restrict__ Gh, unsigned short* __restrict__ Gl,
    unsigned short* __restrict__ Mh, unsigned short* __restrict__ Ml,
    float* __restrict__ scale2, float* __restrict__ bias2)
{
    __shared__ float lds0[2176];   // 128x16 pad17 (8704 B) or 16x128 pad132
    __shared__ float lds1[2176];   // 128x16 pad17
    const int tid = threadIdx.x;
    const int bid = blockIdx.x;

    if (bid == 192) {                              // constants
        if (tid < 128) {
            float sc = bn_gamma[tid] * rsqrtf(bn_var[tid] + 1e-5f);
            scale2[tid] = sc;
            bias2[tid]  = (conv_b[tid] - bn_mean[tid]) * sc + bn_beta[tid];
        }
        return;
    }

    if (bid < 64) {                                // ---- G tile (i0, j0)
        int i0 = (bid >> 3) << 4, j0 = (bid & 7) << 4;
        #pragma unroll
        for (int t = 0; t < 8; ++t) {              // stage col-tiles, 64B lines
            int e = tid + t * 256;
            int o = e >> 4, c = e & 15;
            lds0[o * 17 + c] = Wk[o * 128 + i0 + c];
            lds1[o * 17 + c] = Wq[o * 128 + j0 + c];
        }
        __syncthreads();
        int ti = tid >> 4, tj = tid & 15;          // ti: 4-addr broadcast, tj: 16 banks
        float sum = 0.f;
        #pragma unroll 8
        for (int o = 0; o < 128; ++o) sum += lds0[o * 17 + ti] * lds1[o * 17 + tj];
        float val = sum * 0.08838834764831845f;    // 1/sqrt(128)
        unsigned short h = f2bf(val);
        int idx = (i0 + ti) * 128 + j0 + tj;
        Gh[idx] = h;
        Gl[idx] = f2bf(val - bf2f(h));
    } else {                                       // ---- M tile (o0, c0)
        int rel = bid - 64;
        int o0 = (rel >> 4) << 4, c0 = (rel & 15) << 4;
        int cw0 = (c0 >> 7) << 7, cc0 = c0 & 127;
        #pragma unroll
        for (int t = 0; t < 8; ++t) {
            int e = tid + t * 256;
            int to = e >> 7, k = e & 127;          // conv_w rows: contiguous
            lds0[to * 132 + k] = conv_w[(o0 + to) * 256 + cw0 + k];
            int kk = e >> 4, c = e & 15;           // Wv col-tile
            lds1[kk * 17 + c] = Wv[kk * 128 + cc0 + c];
        }
        __syncthreads();
        int to = tid >> 4, tc = tid & 15;
        float sum = 0.f;
        #pragma unroll 8
        for (int k = 0; k < 128; ++k) sum += lds0[to * 132 + k] * lds1[k * 17 + tc];
        float val = sum * 0.7071067811865476f;     // inv_sqrt2
        unsigned short h = f2bf(val);
        int idx = (o0 + to) * 256 + c0 + tc;
        Mh[idx] = h;
        Ml[idx] = f2bf(val - bf2f(h));
    }
}

// ---------------------------------------------------------------------------
// K1: fused attention + IDWT + conv + BN + LeakyReLU.  32 samples/block,
// 1024 blocks, LDS = 32 KB -> up to 5 blocks/CU (occupancy fix vs r2).
//   bid: samples [32*bid, +32), out group g = bid>>4, j0 = (bid&15)*64.
//   (output col j = 2*b_loc + parity + j0; rows = all 128 channels o)
// LDS: [0,16K)  phase0 y fp32 (32 x 512B, XOR-swizzled granules)
//               phase1+ U-low bf16 (64 rows x 128 c, UADDR swizzle)
//      [16K,32K) phase0b gbuf fp32 (32 x 128) -> phase1+ U-high bf16
// Barriers: after y staging, after phase 0b (g col-halves cross waves).
// Phase1/2 are wave-private (wave w: samples [8w,8w+8), U rows [16w,16w+16)).
// ---------------------------------------------------------------------------
#define UADDR(row, lane) (((row) << 8) + (((((lane) >> 2) ^ ((row) & 7))) << 4) + ((((lane) << 2)) & 15))
#define AADDR(row, gi)   (((row) << 8) + ((((gi) ^ ((row) & 7))) << 4))

__global__ __launch_bounds__(256) void fused_kernel(
    const float* __restrict__ x, const float* __restrict__ y,
    const unsigned short* __restrict__ Gh, const unsigned short* __restrict__ Gl,
    const unsigned short* __restrict__ Mh, const unsigned short* __restrict__ Ml,
    const float* __restrict__ scale2, const float* __restrict__ bias2,
    float* __restrict__ out)
{
    __shared__ __align__(16) unsigned char smem[32768];
    float* gbufF = (float*)(smem + 16384);

    const int tid = threadIdx.x;
    const int w = tid >> 6;          // wave 0..3
    const int l = tid & 63;          // lane
    const int quad = l >> 4;
    const int bid = blockIdx.x;
    const int b0 = bid * 32;

    // ---- Phase 0a: stage y rows [b0,b0+32) fp32, 16B-granule XOR swizzle
    {
        const float* yb = y + (size_t)b0 * 128;
        #pragma unroll
        for (int it = 0; it < 4; ++it) {
            int idx = tid + it * 256;          // 1024 = 32 rows * 32 granules
            int row = idx >> 5, q = idx & 31;
            float4 v = *(const float4*)(yb + row * 128 + q * 4);
            *(float4*)(smem + row * 512 + ((q ^ (row & 7)) << 4)) = v;
        }
    }
    __syncthreads();

    // ---- Phase 0b: g = Y @ G^T (split precision).
    // wave w: sample tile rw=w&1 ([16rw,16rw+16)), col half ch=w>>1 (i in [64ch,+64))
    {
        const int rw = w & 1, ch = w >> 1;
        f32x4 accg[4];
        #pragma unroll
        for (int n = 0; n < 4; ++n) accg[n] = (f32x4){0.f, 0.f, 0.f, 0.f};
        const int yrow = 16 * rw + (l & 15);
        #pragma unroll
        for (int ks = 0; ks < 4; ++ks) {
            int g0 = ks * 8 + quad * 2;
            float4 v0 = *(const float4*)(smem + yrow * 512 + (((g0 + 0) ^ (yrow & 7)) << 4));
            float4 v1 = *(const float4*)(smem + yrow * 512 + (((g0 + 1) ^ (yrow & 7)) << 4));
            float f[8] = {v0.x, v0.y, v0.z, v0.w, v1.x, v1.y, v1.z, v1.w};
            union { bf16x8 v; unsigned short u[8]; } Ah, Al;
            #pragma unroll
            for (int j = 0; j < 8; ++j) {
                unsigned short h = f2bf(f[j]);
                Ah.u[j] = h;
                Al.u[j] = f2bf(f[j] - bf2f(h));
            }
            #pragma unroll
            for (int n = 0; n < 4; ++n) {
                int nt = ch * 4 + n;
                int off = (nt * 16 + (l & 15)) * 128 + ks * 32 + quad * 8;
                bf16x8 bh = *(const bf16x8*)(Gh + off);
                bf16x8 bl = *(const bf16x8*)(Gl + off);
                accg[n] = __builtin_amdgcn_mfma_f32_16x16x32_bf16(Ah.v, bh, accg[n], 0, 0, 0);
                accg[n] = __builtin_amdgcn_mfma_f32_16x16x32_bf16(Al.v, bh, accg[n], 0, 0, 0);
                accg[n] = __builtin_amdgcn_mfma_f32_16x16x32_bf16(Ah.v, bl, accg[n], 0, 0, 0);
            }
        }
        // C-frag: col = l&15 (i), row = quad*4+r (sample) -> gbuf fp32
        #pragma unroll
        for (int n = 0; n < 4; ++n) {
            int i = (ch * 4 + n) * 16 + (l & 15);
            #pragma unroll
            for (int r = 0; r < 4; ++r)
                gbufF[(16 * rw + quad * 4 + r) * 128 + i] = accg[n][r];
        }
    }
    __syncthreads();   // g rows assembled from two waves' col-halves

    // ---- Phase 1: dots (fp32) + softmax + build U (wave-private from here)
    #pragma unroll 4
    for (int s = 0; s < 8; ++s) {
        int b_loc = 8 * w + s;
        const float2* xb = (const float2*)(x + (size_t)(b0 + b_loc) * 512);
        float2 x0 = xb[l], x1 = xb[64 + l], x2 = xb[128 + l], x3 = xb[192 + l];
        float2 g2 = *(const float2*)(gbufF + b_loc * 128 + 2 * l);
        float p0 = x0.x * g2.x + x0.y * g2.y;
        float p1 = x1.x * g2.x + x1.y * g2.y;
        float p2 = x2.x * g2.x + x2.y * g2.y;
        float p3 = x3.x * g2.x + x3.y * g2.y;
        #pragma unroll
        for (int off = 32; off >= 1; off >>= 1) {
            p0 += __shfl_xor(p0, off);
            p1 += __shfl_xor(p1, off);
            p2 += __shfl_xor(p2, off);
            p3 += __shfl_xor(p3, off);
        }
        float mx = fmaxf(fmaxf(p0, p1), fmaxf(p2, p3));
        float e0 = __expf(p0 - mx), e1 = __expf(p1 - mx);
        float e2 = __expf(p2 - mx), e3 = __expf(p3 - mx);
        float inv = 1.f / (e0 + e1 + e2 + e3);
        float w0 = e0 * inv, w1 = e1 * inv, w2 = e2 * inv, w3 = e3 * inv;
        int r0 = 2 * b_loc, r1 = r0 + 1;
        // U-low (region A; overwrites y rows this wave's samples no longer need)
        *(uint32_t*)(smem + UADDR(r0, l)) = pack2bf(w0 * x0.x + w1 * x1.x, w0 * x0.y + w1 * x1.y);
        *(uint32_t*)(smem + UADDR(r1, l)) = pack2bf(w0 * x0.x - w1 * x1.x, w0 * x0.y - w1 * x1.y);
        // U-high (region B; overwrites exactly this sample's gbuf row, read above)
        *(uint32_t*)(smem + 16384 + UADDR(r0, l)) = pack2bf(w2 * x2.x + w3 * x3.x, w2 * x2.y + w3 * x3.y);
        *(uint32_t*)(smem + 16384 + UADDR(r1, l)) = pack2bf(w2 * x2.x - w3 * x3.x, w2 * x2.y - w3 * x3.y);
    }

    // ---- Phase 2: Z = U @ M^T (K=256: low half region A, high half region B),
    // M split hi/lo. Wave w owns U rows [16w,16w+16) -> one 16-row MFMA block.
    f32x4 acc[8];
    #pragma unroll
    for (int nt = 0; nt < 8; ++nt) acc[nt] = (f32x4){0.f, 0.f, 0.f, 0.f};

    #pragma unroll
    for (int ks = 0; ks < 8; ++ks) {
        int half = ks >> 2, kk = ks & 3;
        int base = half << 14;                     // 0 or 16384
        int row0 = 16 * w + (l & 15);
        int gi = kk * 4 + quad;
        bf16x8 a0 = *(const bf16x8*)(smem + base + AADDR(row0, gi));
        #pragma unroll
        for (int nt = 0; nt < 8; ++nt) {
            int off = (nt * 16 + (l & 15)) * 256 + half * 128 + kk * 32 + quad * 8;
            bf16x8 bh = *(const bf16x8*)(Mh + off);
            bf16x8 bl = *(const bf16x8*)(Ml + off);
            acc[nt] = __builtin_amdgcn_mfma_f32_16x16x32_bf16(a0, bh, acc[nt], 0, 0, 0);
            acc[nt] = __builtin_amdgcn_mfma_f32_16x16x32_bf16(a0, bl, acc[nt], 0, 0, 0);
        }
    }

    // ---- Epilogue: scale/bias/LeakyReLU, j-contiguous float4 stores
    {
        float* outp = out + (size_t)(bid >> 4) * 131072 + (bid & 15) * 64;
        int jb = 16 * w + quad * 4;
        #pragma unroll
        for (int nt = 0; nt < 8; ++nt) {
            int o = nt * 16 + (l & 15);
            float sc = scale2[o], bi = bias2[o];
            f32x4 a = acc[nt];
            float4 r;
            r.x = lrelu(a[0] * sc + bi);
            r.y = lrelu(a[1] * sc + bi);
            r.z = lrelu(a[2] * sc + bi);
            r.w = lrelu(a[3] * sc + bi);
            *(float4*)(outp + (size_t)o * 1024 + jb) = r;
        }
    }
}

extern "C" void kernel_launch(void* const* d_in, const int* in_sizes, int n_in,
                              void* d_out, int out_size, void* d_ws, size_t ws_size,
                              hipStream_t stream)
{
    (void)in_sizes; (void)n_in; (void)out_size; (void)ws_size;
    const float* x        = (const float*)d_in[0];
    const float* y        = (const float*)d_in[1];
    const float* Wq       = (const float*)d_in[2];
    const float* Wk       = (const float*)d_in[3];
    const float* Wv       = (const float*)d_in[4];
    const float* conv_w   = (const float*)d_in[5];
    const float* conv_b   = (const float*)d_in[6];
    const float* bn_gamma = (const float*)d_in[7];
    const float* bn_beta  = (const float*)d_in[8];
    const float* bn_mean  = (const float*)d_in[9];
    const float* bn_var   = (const float*)d_in[10];

    unsigned char* ws = (unsigned char*)d_ws;
    unsigned short* Gh = (unsigned short*)(ws);                // 32 KB
    unsigned short* Gl = (unsigned short*)(ws + 32768);        // 32 KB
    unsigned short* Mh = (unsigned short*)(ws + 65536);        // 64 KB
    unsigned short* Ml = (unsigned short*)(ws + 131072);       // 64 KB
    float* scale2      = (float*)(ws + 196608);                // 512 B
    float* bias2       = (float*)(ws + 197120);                // 512 B

    hipLaunchKernelGGL(precompute_kernel, dim3(193), dim3(256), 0, stream,
                       Wq, Wk, Wv, conv_w, conv_b, bn_gamma, bn_beta, bn_mean,
                       bn_var, Gh, Gl, Mh, Ml, scale2, bias2);
    hipLaunchKernelGGL(fused_kernel, dim3(1024), dim3(256), 0, stream,
                       x, y, Gh, Gl, Mh, Ml, scale2, bias2, (float*)d_out);
}

// Round 4
// 154.343 us; speedup vs baseline: 1.2948x; 1.2948x over previous
//
#include <hip/hip_runtime.h>
#include <stdint.h>

// Problem constants
//  B = 32768 samples, T_X = 4, K = 128, 64 groups x 512, out = (64,128,1,1024) fp32
typedef __attribute__((ext_vector_type(8))) short bf16x8;  // 8 bf16 in 4 VGPRs
typedef __attribute__((ext_vector_type(4))) float f32x4;

__device__ __forceinline__ unsigned short f2bf(float x) {
    union { float f; uint32_t u; } v; v.f = x;
    uint32_t r = v.u + 0x7FFFu + ((v.u >> 16) & 1u);   // RNE
    return (unsigned short)(r >> 16);
}
__device__ __forceinline__ uint32_t pack2bf(float a, float b) {
    return (uint32_t)f2bf(a) | ((uint32_t)f2bf(b) << 16);
}
__device__ __forceinline__ float bf2f(uint32_t lo) {
    union { uint32_t u; float f; } v; v.u = lo << 16; return v.f;
}
__device__ __forceinline__ float lrelu(float v) { return v > 0.f ? v : 0.01f * v; }

// ---------------------------------------------------------------------------
// K0: precompute (LDS-tiled small GEMMs, coalesced staging, split hi/lo out)
//   G[i][j]  = (1/sqrt(128)) * sum_o Wk[o,i]*Wq[o,j]             (128x128)
//   M[o][c]  = inv_sqrt2 * sum_k conv_w[o, (c>>7)*128+k]*Wv[k, c&127] (128x256)
//   blocks 0..63: G 16x16 tiles; 64..191: M 16x16 tiles; 192: BN constants
// ---------------------------------------------------------------------------
__global__ __launch_bounds__(256) void precompute_kernel(
    const float* __restrict__ Wq, const float* __restrict__ Wk,
    const float* __restrict__ Wv, const float* __restrict__ conv_w,
    const float* __restrict__ conv_b, const float* __restrict__ bn_gamma,
    const float* __restrict__ bn_beta, const float* __restrict__ bn_mean,
    const float* __restrict__ bn_var,
    unsigned short* __restrict__ Gh, unsigned short* __restrict__ Gl,
    unsigned short* __restrict__ Mh, unsigned short* __restrict__ Ml,
    float* __restrict__ scale2, float* __restrict__ bias2)
{
    __shared__ float lds0[2176];   // 128x16 pad17 (8704 B) or 16x128 pad132
    __shared__ float lds1[2176];   // 128x16 pad17
    const int tid = threadIdx.x;
    const int bid = blockIdx.x;

    if (bid == 192) {                              // constants
        if (tid < 128) {
            float sc = bn_gamma[tid] * rsqrtf(bn_var[tid] + 1e-5f);
            scale2[tid] = sc;
            bias2[tid]  = (conv_b[tid] - bn_mean[tid]) * sc + bn_beta[tid];
        }
        return;
    }

    if (bid < 64) {                                // ---- G tile (i0, j0)
        int i0 = (bid >> 3) << 4, j0 = (bid & 7) << 4;
        #pragma unroll
        for (int t = 0; t < 8; ++t) {              // stage col-tiles, 64B lines
            int e = tid + t * 256;
            int o = e >> 4, c = e & 15;
            lds0[o * 17 + c] = Wk[o * 128 + i0 + c];
            lds1[o * 17 + c] = Wq[o * 128 + j0 + c];
        }
        __syncthreads();
        int ti = tid >> 4, tj = tid & 15;
        float sum = 0.f;
        #pragma unroll 8
        for (int o = 0; o < 128; ++o) sum += lds0[o * 17 + ti] * lds1[o * 17 + tj];
        float val = sum * 0.08838834764831845f;    // 1/sqrt(128)
        unsigned short h = f2bf(val);
        int idx = (i0 + ti) * 128 + j0 + tj;
        Gh[idx] = h;
        Gl[idx] = f2bf(val - bf2f(h));
    } else {                                       // ---- M tile (o0, c0)
        int rel = bid - 64;
        int o0 = (rel >> 4) << 4, c0 = (rel & 15) << 4;
        int cw0 = (c0 >> 7) << 7, cc0 = c0 & 127;
        #pragma unroll
        for (int t = 0; t < 8; ++t) {
            int e = tid + t * 256;
            int to = e >> 7, k = e & 127;          // conv_w rows: contiguous
            lds0[to * 132 + k] = conv_w[(o0 + to) * 256 + cw0 + k];
            int kk = e >> 4, c = e & 15;           // Wv col-tile
            lds1[kk * 17 + c] = Wv[kk * 128 + cc0 + c];
        }
        __syncthreads();
        int to = tid >> 4, tc = tid & 15;
        float sum = 0.f;
        #pragma unroll 8
        for (int k = 0; k < 128; ++k) sum += lds0[to * 132 + k] * lds1[k * 17 + tc];
        float val = sum * 0.7071067811865476f;     // inv_sqrt2
        unsigned short h = f2bf(val);
        int idx = (o0 + to) * 256 + c0 + tc;
        Mh[idx] = h;
        Ml[idx] = f2bf(val - bf2f(h));
    }
}

// ---------------------------------------------------------------------------
// K1: fused attention + IDWT + conv + BN + LeakyReLU.  32 samples/block,
// 1024 blocks, LDS = 32 KB (up to 5 blocks/CU).
// Wave assignment is COLUMN-split in the weight GEMMs so each B-frag load
// feeds the max MFMAs and the block's 4 waves read disjoint weight regions:
//   phase 0b: wave w -> g cols [32w,+32), both 16-sample tiles (G: 16KB/wave)
//   phase 2 : wave w -> channels [32w,+32), all 4 U-row blocks (M: 32KB/wave)
// Per-block ks rotation decorrelates concurrent L2 addresses across blocks.
// LDS: [0,16K)  phase0 y fp32 (32 x 512B, XOR-swizzled granules)
//               phase1+ U-low bf16 (64 rows x 128 c, UADDR swizzle)
//      [16K,32K) phase0b gbuf fp32 (32 x 128) -> phase1+ U-high bf16
// Barriers: after y staging, after 0b, after phase 1 (U is cross-wave in ph2).
// ---------------------------------------------------------------------------
#define UADDR(row, lane) (((row) << 8) + (((((lane) >> 2) ^ ((row) & 7))) << 4) + ((((lane) << 2)) & 15))
#define AADDR(row, gi)   (((row) << 8) + ((((gi) ^ ((row) & 7))) << 4))

__global__ __launch_bounds__(256) void fused_kernel(
    const float* __restrict__ x, const float* __restrict__ y,
    const unsigned short* __restrict__ Gh, const unsigned short* __restrict__ Gl,
    const unsigned short* __restrict__ Mh, const unsigned short* __restrict__ Ml,
    const float* __restrict__ scale2, const float* __restrict__ bias2,
    float* __restrict__ out)
{
    __shared__ __align__(16) unsigned char smem[32768];
    float* gbufF = (float*)(smem + 16384);

    const int tid = threadIdx.x;
    const int w = tid >> 6;          // wave 0..3
    const int l = tid & 63;          // lane
    const int quad = l >> 4;
    const int bid = blockIdx.x;
    const int b0 = bid * 32;

    // ---- Phase 0a: stage y rows [b0,b0+32) fp32, 16B-granule XOR swizzle
    {
        const float* yb = y + (size_t)b0 * 128;
        #pragma unroll
        for (int it = 0; it < 4; ++it) {
            int idx = tid + it * 256;          // 1024 = 32 rows * 32 granules
            int row = idx >> 5, q = idx & 31;
            float4 v = *(const float4*)(yb + row * 128 + q * 4);
            *(float4*)(smem + row * 512 + ((q ^ (row & 7)) << 4)) = v;
        }
    }
    __syncthreads();

    // ---- Phase 0b: g = Y @ G^T (split precision), column-split waves.
    {
        f32x4 accg[2][2];    // [sample-tile rt][col-block n]
        #pragma unroll
        for (int rt = 0; rt < 2; ++rt)
            #pragma unroll
            for (int n = 0; n < 2; ++n) accg[rt][n] = (f32x4){0.f, 0.f, 0.f, 0.f};
        #pragma unroll
        for (int ks = 0; ks < 4; ++ks) {
            int ksr = (ks + bid) & 3;                    // per-block rotation
            union { bf16x8 v; unsigned short u[8]; } Ah[2], Al[2];
            #pragma unroll
            for (int rt = 0; rt < 2; ++rt) {
                int yrow = 16 * rt + (l & 15);
                int g0 = ksr * 8 + quad * 2;
                float4 v0 = *(const float4*)(smem + yrow * 512 + (((g0 + 0) ^ (yrow & 7)) << 4));
                float4 v1 = *(const float4*)(smem + yrow * 512 + (((g0 + 1) ^ (yrow & 7)) << 4));
                float f[8] = {v0.x, v0.y, v0.z, v0.w, v1.x, v1.y, v1.z, v1.w};
                #pragma unroll
                for (int j = 0; j < 8; ++j) {
                    unsigned short h = f2bf(f[j]);
                    Ah[rt].u[j] = h;
                    Al[rt].u[j] = f2bf(f[j] - bf2f(h));
                }
            }
            #pragma unroll
            for (int n = 0; n < 2; ++n) {
                int nt = 2 * w + n;
                int off = (nt * 16 + (l & 15)) * 128 + ksr * 32 + quad * 8;
                bf16x8 bh = *(const bf16x8*)(Gh + off);
                bf16x8 bl = *(const bf16x8*)(Gl + off);
                #pragma unroll
                for (int rt = 0; rt < 2; ++rt) {
                    accg[rt][n] = __builtin_amdgcn_mfma_f32_16x16x32_bf16(Ah[rt].v, bh, accg[rt][n], 0, 0, 0);
                    accg[rt][n] = __builtin_amdgcn_mfma_f32_16x16x32_bf16(Al[rt].v, bh, accg[rt][n], 0, 0, 0);
                    accg[rt][n] = __builtin_amdgcn_mfma_f32_16x16x32_bf16(Ah[rt].v, bl, accg[rt][n], 0, 0, 0);
                }
            }
        }
        // C-frag: col = l&15 (i offset), row = quad*4+r (sample) -> gbuf fp32
        #pragma unroll
        for (int n = 0; n < 2; ++n) {
            int i = (2 * w + n) * 16 + (l & 15);
            #pragma unroll
            for (int rt = 0; rt < 2; ++rt)
                #pragma unroll
                for (int r = 0; r < 4; ++r)
                    gbufF[(16 * rt + quad * 4 + r) * 128 + i] = accg[rt][n][r];
        }
    }
    __syncthreads();   // g rows assembled from all four waves' col-blocks

    // ---- Phase 1: dots (fp32) + softmax + build U. Wave-private LDS ranges:
    // wave w: samples [8w,8w+8), U rows [16w,+16) in both halves (byte range
    // [4096w,+4096) in each region == exactly the gbuf rows it just read).
    #pragma unroll 4
    for (int s = 0; s < 8; ++s) {
        int b_loc = 8 * w + s;
        const float2* xb = (const float2*)(x + (size_t)(b0 + b_loc) * 512);
        float2 x0 = xb[l], x1 = xb[64 + l], x2 = xb[128 + l], x3 = xb[192 + l];
        float2 g2 = *(const float2*)(gbufF + b_loc * 128 + 2 * l);
        float p0 = x0.x * g2.x + x0.y * g2.y;
        float p1 = x1.x * g2.x + x1.y * g2.y;
        float p2 = x2.x * g2.x + x2.y * g2.y;
        float p3 = x3.x * g2.x + x3.y * g2.y;
        #pragma unroll
        for (int off = 32; off >= 1; off >>= 1) {
            p0 += __shfl_xor(p0, off);
            p1 += __shfl_xor(p1, off);
            p2 += __shfl_xor(p2, off);
            p3 += __shfl_xor(p3, off);
        }
        float mx = fmaxf(fmaxf(p0, p1), fmaxf(p2, p3));
        float e0 = __expf(p0 - mx), e1 = __expf(p1 - mx);
        float e2 = __expf(p2 - mx), e3 = __expf(p3 - mx);
        float inv = 1.f / (e0 + e1 + e2 + e3);
        float w0 = e0 * inv, w1 = e1 * inv, w2 = e2 * inv, w3 = e3 * inv;
        int r0 = 2 * b_loc, r1 = r0 + 1;
        *(uint32_t*)(smem + UADDR(r0, l)) = pack2bf(w0 * x0.x + w1 * x1.x, w0 * x0.y + w1 * x1.y);
        *(uint32_t*)(smem + UADDR(r1, l)) = pack2bf(w0 * x0.x - w1 * x1.x, w0 * x0.y - w1 * x1.y);
        *(uint32_t*)(smem + 16384 + UADDR(r0, l)) = pack2bf(w2 * x2.x + w3 * x3.x, w2 * x2.y + w3 * x3.y);
        *(uint32_t*)(smem + 16384 + UADDR(r1, l)) = pack2bf(w2 * x2.x - w3 * x3.x, w2 * x2.y - w3 * x3.y);
    }
    __syncthreads();   // phase 2 reads all waves' U rows

    // ---- Phase 2: Z = U @ M^T (K=256), column-split waves: wave w owns
    // channels [32w,+32), all 4 row-blocks -> each B pair feeds 8 MFMAs.
    f32x4 acc[4][2];   // [row-block rb][col-block n]
    #pragma unroll
    for (int rb = 0; rb < 4; ++rb)
        #pragma unroll
        for (int n = 0; n < 2; ++n) acc[rb][n] = (f32x4){0.f, 0.f, 0.f, 0.f};

    #pragma unroll
    for (int ks = 0; ks < 8; ++ks) {
        int ksr = (ks + bid) & 7;                  // per-block rotation
        int half = ksr >> 2, kk = ksr & 3;
        int base = half << 14;                     // 0 or 16384
        int gi = kk * 4 + quad;
        bf16x8 a[4];
        #pragma unroll
        for (int rb = 0; rb < 4; ++rb)
            a[rb] = *(const bf16x8*)(smem + base + AADDR(16 * rb + (l & 15), gi));
        #pragma unroll
        for (int n = 0; n < 2; ++n) {
            int off = ((2 * w + n) * 16 + (l & 15)) * 256 + half * 128 + kk * 32 + quad * 8;
            bf16x8 bh = *(const bf16x8*)(Mh + off);
            bf16x8 bl = *(const bf16x8*)(Ml + off);
            #pragma unroll
            for (int rb = 0; rb < 4; ++rb) {
                acc[rb][n] = __builtin_amdgcn_mfma_f32_16x16x32_bf16(a[rb], bh, acc[rb][n], 0, 0, 0);
                acc[rb][n] = __builtin_amdgcn_mfma_f32_16x16x32_bf16(a[rb], bl, acc[rb][n], 0, 0, 0);
            }
        }
    }

    // ---- Epilogue: scale/bias/LeakyReLU, j-contiguous float4 stores
    {
        float* outp = out + (size_t)(bid >> 4) * 131072 + (bid & 15) * 64;
        #pragma unroll
        for (int n = 0; n < 2; ++n) {
            int o = (2 * w + n) * 16 + (l & 15);
            float sc = scale2[o], bi = bias2[o];
            #pragma unroll
            for (int rb = 0; rb < 4; ++rb) {
                int jb = 16 * rb + quad * 4;
                f32x4 a = acc[rb][n];
                float4 r;
                r.x = lrelu(a[0] * sc + bi);
                r.y = lrelu(a[1] * sc + bi);
                r.z = lrelu(a[2] * sc + bi);
                r.w = lrelu(a[3] * sc + bi);
                *(float4*)(outp + (size_t)o * 1024 + jb) = r;
            }
        }
    }
}

extern "C" void kernel_launch(void* const* d_in, const int* in_sizes, int n_in,
                              void* d_out, int out_size, void* d_ws, size_t ws_size,
                              hipStream_t stream)
{
    (void)in_sizes; (void)n_in; (void)out_size; (void)ws_size;
    const float* x        = (const float*)d_in[0];
    const float* y        = (const float*)d_in[1];
    const float* Wq       = (const float*)d_in[2];
    const float* Wk       = (const float*)d_in[3];
    const float* Wv       = (const float*)d_in[4];
    const float* conv_w   = (const float*)d_in[5];
    const float* conv_b   = (const float*)d_in[6];
    const float* bn_gamma = (const float*)d_in[7];
    const float* bn_beta  = (const float*)d_in[8];
    const float* bn_mean  = (const float*)d_in[9];
    const float* bn_var   = (const float*)d_in[10];

    unsigned char* ws = (unsigned char*)d_ws;
    unsigned short* Gh = (unsigned short*)(ws);                // 32 KB
    unsigned short* Gl = (unsigned short*)(ws + 32768);        // 32 KB
    unsigned short* Mh = (unsigned short*)(ws + 65536);        // 64 KB
    unsigned short* Ml = (unsigned short*)(ws + 131072);       // 64 KB
    float* scale2      = (float*)(ws + 196608);                // 512 B
    float* bias2       = (float*)(ws + 197120);                // 512 B

    hipLaunchKernelGGL(precompute_kernel, dim3(193), dim3(256), 0, stream,
                       Wq, Wk, Wv, conv_w, conv_b, bn_gamma, bn_beta, bn_mean,
                       bn_var, Gh, Gl, Mh, Ml, scale2, bias2);
    hipLaunchKernelGGL(fused_kernel, dim3(1024), dim3(256), 0, stream,
                       x, y, Gh, Gl, Mh, Ml, scale2, bias2, (float*)d_out);
}